// Round 10
// baseline (133.519 us; speedup 1.0000x reference)
//
#include <hip/hip_runtime.h>

typedef __bf16 bf16_t;
typedef bf16_t bf16x8 __attribute__((ext_vector_type(8)));
typedef float f32x4 __attribute__((ext_vector_type(4)));
typedef unsigned short ushort_t;
typedef unsigned int uint_t;

#define C10L2E 14.4269504088896340736f   // 10 * log2(e)
#define LN2    0.69314718055994530942f
#define NEG_BIG -3.0e38f
#define M0     -1.0e30f

static __device__ __forceinline__ float fexp2(float x){ return __builtin_amdgcn_exp2f(x); }
static __device__ __forceinline__ float flog2(float x){ return __builtin_amdgcn_logf(x); }

#define GLOAD16(g, l) __builtin_amdgcn_global_load_lds( \
    (const __attribute__((address_space(1))) void*)(g), \
    (__attribute__((address_space(3))) void*)(l), 16, 0, 0)

// ---------------- fp32 -> bf16 (RNE) ----------------
static __device__ __forceinline__ ushort_t f2bf1(float f) {
    uint_t u = __float_as_uint(f);
    uint_t r = (u + 0x7fffu + ((u >> 16) & 1u)) >> 16;
    return (ushort_t)r;
}

// ---------------- prep: bf16 convert + label scatter (R3-proven) ----------------
__global__ void prep_kernel(const float* __restrict__ feat, const int* __restrict__ labels,
                            ushort_t* __restrict__ Fb, int* __restrict__ cnt,
                            int* __restrict__ idxl) {
    int i = blockIdx.x * 256 + threadIdx.x;        // 0..524287 float4s
    float4 f = reinterpret_cast<const float4*>(feat)[i];
    ushort4 o;
    o.x = f2bf1(f.x); o.y = f2bf1(f.y); o.z = f2bf1(f.z); o.w = f2bf1(f.w);
    reinterpret_cast<ushort4*>(Fb)[i] = o;
    if (i < 4096) {
        int lab = labels[i];
        int p = atomicAdd(&cnt[lab], 1);
        if (p < 64) idxl[lab * 64 + p] = i;
    }
}

// ---------------- per-class term (R3-proven, 1000 x 64): (|G|^2 - sum|f|^2)/(2n-1) ----
__global__ void classterm_kernel(const float* __restrict__ feat, const int* __restrict__ cnt,
                                 const int* __restrict__ idxl, float* __restrict__ term) {
    int c = blockIdx.x;
    int lane = threadIdx.x;                         // 0..63
    int n = cnt[c];
    int ne = n < 64 ? n : 64;                       // clamp (rocprof-replay safety)
    float4 g4 = make_float4(0.f, 0.f, 0.f, 0.f);
    float n2 = 0.f;
    for (int e = 0; e < ne; ++e) {
        int r = idxl[c * 64 + e];
        float4 f0 = reinterpret_cast<const float4*>(feat)[(size_t)r * 64 + lane];
        float4 f1 = reinterpret_cast<const float4*>(feat)[(size_t)(r + 4096) * 64 + lane];
        g4.x += f0.x + f1.x; g4.y += f0.y + f1.y;
        g4.z += f0.z + f1.z; g4.w += f0.w + f1.w;
        n2 += f0.x*f0.x + f0.y*f0.y + f0.z*f0.z + f0.w*f0.w
            + f1.x*f1.x + f1.y*f1.y + f1.z*f1.z + f1.w*f1.w;
    }
    float gg = g4.x*g4.x + g4.y*g4.y + g4.z*g4.z + g4.w*g4.w;
    #pragma unroll
    for (int d = 1; d < 64; d <<= 1) {
        gg += __shfl_xor(gg, d, 64);
        n2 += __shfl_xor(n2, d, 64);
    }
    if (lane == 0) term[c] = (n > 0) ? (gg - n2) / (float)(2 * n - 1) : 0.0f;
}

// ---------------- main MFMA kernel ----------------
// Grid (64,16) = 1024 blocks, 4 sequential per CU. 512 threads = 8 waves (2 row-groups
// x 4 col-groups), wave tile 64x128 (acc 4x8 of 16x16 -> 128 VGPR, pinned by
// amdgpu_waves_per_eu(2,2)). Block tile: 128 rows x 512 cols, full K=256 in 8 phases
// of K=32. LDS 128KB: A full-K (128x256 bf16, 64KB, R3 XOR swizzle) + B dbuf 2x32KB
// ([512 cols][4 slots of 16B], rotation swizzle phys=(oct+(col>>1))&3 -> 2-way free).
// NO online softmax: acc holds the whole strip's logits; exact max+sum epilogue once,
// after the last barrier. Stage-ahead + __syncthreads per phase (R3-proven pattern).
__global__ __launch_bounds__(512) __attribute__((amdgpu_waves_per_eu(2, 2)))
void supcon_main(const ushort_t* __restrict__ Fb, float2* __restrict__ part) {
    extern __shared__ char lds[];
    char* As = lds;                      // [128 rows][32 slots of 16B]
    char* Bb = lds + 65536;              // 2 x [512 cols][4 slots of 16B]

    const int tid  = threadIdx.x;
    const int lane = tid & 63;
    const int wid  = tid >> 6;
    const int wr   = (wid >> 2) * 64;    // row-group offset
    const int wc   = (wid & 3) * 128;    // col-group offset
    const int g    = lane >> 4;
    const int l15  = lane & 15;
    const int r0 = blockIdx.x * 128;
    const int c0 = blockIdx.y * 512;

    // ---- stage A once (8 chunks/thread), R3 swizzle ----
    #pragma unroll
    for (int i = 0; i < 8; ++i) {
        int c = i * 512 + tid;                     // 0..4095
        int row = c >> 5, sl = c & 31;
        int lslot = (sl & 16) | ((sl ^ row) & 15); // inverse swizzle on source
        GLOAD16(Fb + (size_t)(r0 + row) * 256 + lslot * 8, As + c * 16);
    }

    // ---- B staging geometry (4 chunks/thread), rotation swizzle ----
    int bofs[4], bdst[4];
    #pragma unroll
    for (int i = 0; i < 4; ++i) {
        int c = i * 512 + tid;                     // 0..2047
        int col = c >> 2, ps = c & 3;
        int kslot = (ps - (col >> 1)) & 3;         // inverse rotation on source
        bofs[i] = col * 256 + kslot * 8;           // element offset within col-strip
        bdst[i] = c * 16;
    }
    auto stageB = [&](int p) {                     // phase 0..7 (K-eighth p)
        const ushort_t* base = Fb + (size_t)c0 * 256 + p * 32;
        char* Bd = Bb + (p & 1) * 32768;
        #pragma unroll
        for (int i = 0; i < 4; ++i)
            GLOAD16(base + bofs[i], Bd + bdst[i]);
    };

    stageB(0);
    __syncthreads();                               // A + B0 landed (vmcnt drain)

    f32x4 acc[4][8];
    #pragma unroll
    for (int m = 0; m < 4; ++m)
        #pragma unroll
        for (int n = 0; n < 8; ++n)
            #pragma unroll
            for (int w = 0; w < 4; ++w) acc[m][n][w] = 0.0f;

    #pragma unroll
    for (int p = 0; p < 8; ++p) {
        if (p < 7) stageB(p + 1);

        bf16x8 a[4], b[8];
        const int sA = p * 4 + g;
        const int pA = (sA & 16) | ((sA ^ l15) & 15);
        #pragma unroll
        for (int m = 0; m < 4; ++m)
            a[m] = *reinterpret_cast<const bf16x8*>(As + (wr + m * 16 + l15) * 512 + pA * 16);
        const char* Bp = Bb + (p & 1) * 32768;
        #pragma unroll
        for (int n = 0; n < 8; ++n) {
            int col = wc + n * 16 + l15;
            int phys = (g + (col >> 1)) & 3;
            b[n] = *reinterpret_cast<const bf16x8*>(Bp + col * 64 + phys * 16);
        }
        #pragma unroll
        for (int m = 0; m < 4; ++m)
            #pragma unroll
            for (int n = 0; n < 8; ++n)
                acc[m][n] = __builtin_amdgcn_mfma_f32_16x16x32_bf16(a[m], b[n], acc[m][n], 0, 0, 0);

        if (p < 7) __syncthreads();                // buffer p+1 landed; p's readers done
    }

    // ---- exact epilogue (register-local, after last barrier) ----
    const bool diag = (c0 == (r0 & ~511));
    const int jc = c0 + wc + l15;
    float ML2[16], S[16];
    #pragma unroll
    for (int m = 0; m < 4; ++m) {
        #pragma unroll
        for (int v = 0; v < 4; ++v) {
            const int idx = m * 4 + v;
            float x[8];
            #pragma unroll
            for (int n = 0; n < 8; ++n) x[n] = acc[m][n][v];
            if (diag) {
                int i = r0 + wr + m * 16 + g * 4 + v;
                #pragma unroll
                for (int n = 0; n < 8; ++n)
                    if (jc + 16 * n == i) x[n] = NEG_BIG;
            }
            float mx = fmaxf(fmaxf(fmaxf(x[0], x[1]), fmaxf(x[2], x[3])),
                             fmaxf(fmaxf(x[4], x[5]), fmaxf(x[6], x[7])));
            float cc = mx * C10L2E;
            float s = 0.0f;
            #pragma unroll
            for (int n = 0; n < 8; ++n) s += fexp2(fmaf(x[n], C10L2E, -cc));
            ML2[idx] = cc; S[idx] = s;
        }
    }

    // ---- 16-lane merge (cols within quarter-wave), store partials ----
    const int slot = blockIdx.y * 4 + (wid & 3);   // 64 slots per row
    #pragma unroll
    for (int idx = 0; idx < 16; ++idx) {
        float m_ = ML2[idx], s_ = S[idx];
        #pragma unroll
        for (int d = 1; d < 16; d <<= 1) {
            float mo = __shfl_xor(m_, d, 64);
            float so = __shfl_xor(s_, d, 64);
            float nm = fmaxf(m_, mo);
            s_ = s_ * fexp2(m_ - nm) + so * fexp2(mo - nm);
            m_ = nm;
        }
        if (l15 == 0) {
            int i = r0 + wr + (idx >> 2) * 16 + g * 4 + (idx & 3);
            float2 val; val.x = m_; val.y = s_;
            part[(size_t)i * 64 + slot] = val;
        }
    }
}

// ---------------- combine + final (fused): merge 64 slots/row -> lse; atomic total ----
// 2048 blocks x 256 threads; one wave per row (4 rows/block)
__global__ void combine_kernel(const float2* __restrict__ part, const float* __restrict__ term,
                               float* __restrict__ acc, int* __restrict__ cntr,
                               float* __restrict__ out) {
    __shared__ float sm[4];
    int tid = threadIdx.x;
    int r = blockIdx.x * 4 + (tid >> 6);
    int lane = tid & 63;
    float2 v = part[(size_t)r * 64 + lane];
    float m_ = v.x, s_ = v.y;
    #pragma unroll
    for (int d = 1; d < 64; d <<= 1) {
        float mo = __shfl_xor(m_, d, 64);
        float so = __shfl_xor(s_, d, 64);
        float nm = fmaxf(m_, mo);
        s_ = s_ * fexp2(m_ - nm) + so * fexp2(mo - nm);
        m_ = nm;
    }
    if (lane == 0) sm[tid >> 6] = LN2 * (m_ + flog2(s_));
    __syncthreads();
    if (tid == 0) {
        float a = sm[0] + sm[1] + sm[2] + sm[3];
        if (blockIdx.x < 1000) a -= 10.0f * term[blockIdx.x];
        atomicAdd(acc, a);
        __threadfence();
        int old = atomicAdd(cntr, 1);
        if (old == 2047) {
            __threadfence();
            float tot = atomicAdd(acc, 0.0f);
            out[0] = tot * (0.1f / 8192.0f);
        }
    }
}

extern "C" void kernel_launch(void* const* d_in, const int* in_sizes, int n_in,
                              void* d_out, int out_size, void* d_ws, size_t ws_size,
                              hipStream_t stream) {
    const float* feat = (const float*)d_in[0];    // 8192 x 256 fp32
    const int* labels = (const int*)d_in[1];      // 4096
    float* out = (float*)d_out;

    char* ws = (char*)d_ws;
    ushort_t* Fb = (ushort_t*)ws;                                // 4 MB
    float2* part = (float2*)(ws + (4u << 20));                   // 4 MB (8192 x 64 x 8B)
    int* cnt     = (int*)(ws + (8u << 20));                      // 4 KB
    float* acc   = (float*)(ws + (8u << 20) + 4096);             // 4 B
    int* cntr    = (int*)(ws + (8u << 20) + 4100);               // 4 B
    int* idxl    = (int*)(ws + (8u << 20) + 8192);               // 256 KB
    float* term  = (float*)(ws + (8u << 20) + 8192 + 262144);    // 4 KB

    hipMemsetAsync(cnt, 0, 8200, stream);                        // cnt + acc + cntr
    prep_kernel<<<2048, 256, 0, stream>>>(feat, labels, Fb, cnt, idxl);
    classterm_kernel<<<1000, 64, 0, stream>>>(feat, cnt, idxl, term);
    dim3 grid(64, 16);
    supcon_main<<<grid, 512, 131072, stream>>>(Fb, part);
    combine_kernel<<<2048, 256, 0, stream>>>(part, term, acc, cntr, out);
}

// Round 11
// 87.849 us; speedup vs baseline: 1.5199x; 1.5199x over previous
//
#include <hip/hip_runtime.h>

typedef __bf16 bf16_t;
typedef bf16_t bf16x8 __attribute__((ext_vector_type(8)));
typedef float f32x4 __attribute__((ext_vector_type(4)));
typedef unsigned short ushort_t;
typedef unsigned int uint_t;

#define C10L2E 14.4269504088896340736f   // 10 * log2(e)
#define LN2    0.69314718055994530942f
#define NEG_BIG -3.0e38f
#define M0     -1.0e30f
#define THR_L2 11.5415603f               // 0.8 raw logit units in log2-space

static __device__ __forceinline__ float fexp2(float x){ return __builtin_amdgcn_exp2f(x); }
static __device__ __forceinline__ float flog2(float x){ return __builtin_amdgcn_logf(x); }

#define GLOAD16(g, l) __builtin_amdgcn_global_load_lds( \
    (const __attribute__((address_space(1))) void*)(g), \
    (__attribute__((address_space(3))) void*)(l), 16, 0, 0)

// ---------------- fp32 -> bf16 (RNE) ----------------
static __device__ __forceinline__ ushort_t f2bf1(float f) {
    uint_t u = __float_as_uint(f);
    uint_t r = (u + 0x7fffu + ((u >> 16) & 1u)) >> 16;
    return (ushort_t)r;
}

// ---------------- prep: bf16 convert + label scatter (R3-proven) ----------------
__global__ void prep_kernel(const float* __restrict__ feat, const int* __restrict__ labels,
                            ushort_t* __restrict__ Fb, int* __restrict__ cnt,
                            int* __restrict__ idxl) {
    int i = blockIdx.x * 256 + threadIdx.x;        // 0..524287 float4s
    float4 f = reinterpret_cast<const float4*>(feat)[i];
    ushort4 o;
    o.x = f2bf1(f.x); o.y = f2bf1(f.y); o.z = f2bf1(f.z); o.w = f2bf1(f.w);
    reinterpret_cast<ushort4*>(Fb)[i] = o;
    if (i < 4096) {
        int lab = labels[i];
        int p = atomicAdd(&cnt[lab], 1);
        if (p < 64) idxl[lab * 64 + p] = i;
    }
}

// ---------------- main MFMA kernel (R3 structure, verbatim — 45.8us, 3x reproduced) ----
// grid (64,4): 256 blocks = 1/CU. 512 threads = 8 waves (2 row-groups x 4 col-groups,
// wave tile 64x64, acc 4x4 of 16x16). Block tile 128 rows x 2048 cols; each block
// sweeps 8 col-tiles x 4 K-quarters = 32 phases.
// LDS 128KB: A full-K (128x256bf16=64KB) + B double-buffered K-quarter (256x64=32KB x2).
// 16B-slot XOR swizzles; staging via global_load_lds with pre-swizzled source.
__global__ __launch_bounds__(512, 2) void supcon_main(
        const ushort_t* __restrict__ Fb, float* __restrict__ part) {
    extern __shared__ char lds[];
    char* As = lds;                                  // [128][32 slots]
    char* Bb0 = lds + 65536;                         // [256][8 slots]
    char* Bb1 = lds + 65536 + 32768;

    const int tid  = threadIdx.x;
    const int lane = tid & 63;
    const int wid  = tid >> 6;
    const int wr   = (wid >> 2) * 64;
    const int wc   = (wid & 3) * 64;
    const int g    = lane >> 4;
    const int l15  = lane & 15;
    const int r0 = blockIdx.x * 128;
    const int c0 = blockIdx.y * 2048;

    // ---- stage A once ----
    #pragma unroll
    for (int i = 0; i < 8; ++i) {
        int c = (wid * 8 + i) * 64 + lane;          // 0..4095
        int row = c >> 5, sl = c & 31;
        int lslot = (sl & 16) | ((sl ^ row) & 15);
        GLOAD16(Fb + (size_t)(r0 + row) * 256 + lslot * 8, As + c * 16);
    }
    // ---- precompute B staging geometry (per thread, 4 chunks) ----
    int bgofs[4], bdst[4];
    #pragma unroll
    for (int i = 0; i < 4; ++i) {
        int c = (wid * 4 + i) * 64 + lane;          // 0..2047
        int col = c >> 3, ps = c & 7;
        int lslot = ps ^ (col & 7);
        bgofs[i] = col * 256 + lslot * 8;           // element offset within a col-tile
        bdst[i] = c * 16;
    }
    // ---- stage B phase 0 ----
    #pragma unroll
    for (int i = 0; i < 4; ++i)
        GLOAD16(Fb + (size_t)c0 * 256 + bgofs[i], Bb0 + bdst[i]);
    __syncthreads();

    float ML2[16], S[16];
    #pragma unroll
    for (int x = 0; x < 16; ++x) { ML2[x] = M0; S[x] = 0.0f; }

    f32x4 acc[4][4];

    auto stage_next = [&](int pn) {
        int j0n = c0 + (pn >> 2) * 256;
        int qn = pn & 3;
        char* Bd = (pn & 1) ? Bb1 : Bb0;
        #pragma unroll
        for (int i = 0; i < 4; ++i)
            GLOAD16(Fb + (size_t)j0n * 256 + qn * 64 + bgofs[i], Bd + bdst[i]);
    };

    auto do_phase = [&](int p, bool ZERO, bool EPI) {
        if (p < 31) stage_next(p + 1);
        if (ZERO) {
            #pragma unroll
            for (int m = 0; m < 4; ++m)
                #pragma unroll
                for (int n = 0; n < 4; ++n)
                    #pragma unroll
                    for (int q_ = 0; q_ < 4; ++q_) acc[m][n][q_] = 0.0f;
        }
        const char* Bp = (p & 1) ? Bb1 : Bb0;
        const int q = p & 3;
        #pragma unroll
        for (int kk = 0; kk < 2; ++kk) {
            int sA = q * 8 + kk * 4 + g;
            int pA = (sA & 16) | ((sA ^ l15) & 15);
            bf16x8 a[4], b[4];
            #pragma unroll
            for (int m = 0; m < 4; ++m)
                a[m] = *reinterpret_cast<const bf16x8*>(As + (wr + m * 16 + l15) * 512 + pA * 16);
            int pB = (kk * 4 + g) ^ (l15 & 7);
            #pragma unroll
            for (int n = 0; n < 4; ++n)
                b[n] = *reinterpret_cast<const bf16x8*>(Bp + (wc + n * 16 + l15) * 128 + pB * 16);
            #pragma unroll
            for (int m = 0; m < 4; ++m)
                #pragma unroll
                for (int n = 0; n < 4; ++n)
                    acc[m][n] = __builtin_amdgcn_mfma_f32_16x16x32_bf16(a[m], b[n], acc[m][n], 0, 0, 0);
        }
        if (EPI) {
            const int j0 = c0 + (p >> 2) * 256;
            const bool diag = (j0 == (r0 & ~255));
            const int jc = j0 + wc + l15;
            #pragma unroll
            for (int m = 0; m < 4; ++m) {
                #pragma unroll
                for (int v = 0; v < 4; ++v) {
                    const int idx = m * 4 + v;
                    float x0 = acc[m][0][v], x1 = acc[m][1][v];
                    float x2 = acc[m][2][v], x3 = acc[m][3][v];
                    if (diag) {
                        int i = r0 + wr + m * 16 + g * 4 + v;
                        if (jc      == i) x0 = NEG_BIG;
                        if (jc + 16 == i) x1 = NEG_BIG;
                        if (jc + 32 == i) x2 = NEG_BIG;
                        if (jc + 48 == i) x3 = NEG_BIG;
                    }
                    float tm = fmaxf(fmaxf(x0, x1), fmaxf(x2, x3));
                    float cc = tm * C10L2E;
                    float ml = ML2[idx];
                    if (cc > ml + THR_L2) {          // rare rescale (defer-max)
                        S[idx] *= fexp2(ml - cc);
                        ml = cc;
                        ML2[idx] = cc;
                    }
                    S[idx] += fexp2(fmaf(x0, C10L2E, -ml)) + fexp2(fmaf(x1, C10L2E, -ml))
                            + fexp2(fmaf(x2, C10L2E, -ml)) + fexp2(fmaf(x3, C10L2E, -ml));
                }
            }
        }
        __syncthreads();
    };

    for (int t = 0; t < 8; ++t) {
        do_phase(t * 4 + 0, true,  false);
        do_phase(t * 4 + 1, false, false);
        do_phase(t * 4 + 2, false, false);
        do_phase(t * 4 + 3, false, true);
    }

    // ---- cross-lane merge within 16-lane groups, store partials ----
    const int slot = blockIdx.y * 4 + (wid & 3);
    #pragma unroll
    for (int idx = 0; idx < 16; ++idx) {
        float m_ = ML2[idx], s_ = S[idx];
        #pragma unroll
        for (int d = 1; d < 16; d <<= 1) {
            float mo = __shfl_xor(m_, d, 64);
            float so = __shfl_xor(s_, d, 64);
            float nm = fmaxf(m_, mo);
            s_ = s_ * fexp2(m_ - nm) + so * fexp2(mo - nm);
            m_ = nm;
        }
        if (l15 == 0) {
            int i = r0 + wr + (idx >> 2) * 16 + g * 4 + (idx & 3);
            float2 val; val.x = m_; val.y = s_;
            *reinterpret_cast<float2*>(part + ((size_t)i * 16 + slot) * 2) = val;
        }
    }
}

// ---------------- combine-all: lse merge + gather-based class term + final ----------------
// 1024 blocks x 256 threads.
//   blocks 0..511 : merge 16 rows' 16-slot partials -> lse sum (256 threads).
//   blocks 0..999 : wave 0 then computes class term for class bx via prep-built
//                   idxl gather: (|G_c|^2 - sum|f|^2)/(2n-1)  (NO label scanning).
// One atomicAdd per block; counter; last block (of 1024) writes the scalar loss.
__global__ __launch_bounds__(256) void combine_kernel(
        const float* __restrict__ part, const float* __restrict__ feat,
        const int* __restrict__ cnt, const int* __restrict__ idxl,
        float* __restrict__ acc, int* __restrict__ cntr, float* __restrict__ out) {
    __shared__ float sm[16];
    __shared__ float tterm;
    const int tid = threadIdx.x;
    const int bx = blockIdx.x;

    // ---- row-lse merge (blocks < 512): 16 rows x 16 slots ----
    if (bx < 512) {
        int row = bx * 16 + (tid >> 4);
        int l16 = tid & 15;
        float2 v = reinterpret_cast<const float2*>(part)[(size_t)row * 16 + l16];
        float m_ = v.x, s_ = v.y;
        #pragma unroll
        for (int d = 1; d < 16; d <<= 1) {
            float mo = __shfl_xor(m_, d, 64);
            float so = __shfl_xor(s_, d, 64);
            float nm = fmaxf(m_, mo);
            s_ = s_ * fexp2(m_ - nm) + so * fexp2(mo - nm);
            m_ = nm;
        }
        if (l16 == 0) sm[tid >> 4] = LN2 * (m_ + flog2(s_));
    }

    // ---- wave 0: class term for class bx (blocks < 1000) ----
    if (bx < 1000 && tid < 64) {
        int n = cnt[bx];
        int ne = n < 64 ? n : 64;
        float4 g4 = make_float4(0.f, 0.f, 0.f, 0.f);
        float n2 = 0.f;
        for (int e = 0; e < ne; ++e) {
            int r = idxl[bx * 64 + e];
            float4 f0 = reinterpret_cast<const float4*>(feat)[(size_t)r * 64 + tid];
            float4 f1 = reinterpret_cast<const float4*>(feat)[(size_t)(r + 4096) * 64 + tid];
            g4.x += f0.x + f1.x; g4.y += f0.y + f1.y;
            g4.z += f0.z + f1.z; g4.w += f0.w + f1.w;
            n2 += f0.x*f0.x + f0.y*f0.y + f0.z*f0.z + f0.w*f0.w
                + f1.x*f1.x + f1.y*f1.y + f1.z*f1.z + f1.w*f1.w;
        }
        float gg = g4.x*g4.x + g4.y*g4.y + g4.z*g4.z + g4.w*g4.w;
        #pragma unroll
        for (int d = 1; d < 64; d <<= 1) {
            gg += __shfl_xor(gg, d, 64);
            n2 += __shfl_xor(n2, d, 64);
        }
        if (tid == 0) tterm = (n > 0) ? (gg - n2) / (float)(2 * n - 1) : 0.0f;
    }
    __syncthreads();   // sm + tterm ready

    if (tid == 0) {
        float a = 0.0f;
        if (bx < 512) {
            #pragma unroll
            for (int i = 0; i < 16; ++i) a += sm[i];
        }
        if (bx < 1000) a -= 10.0f * tterm;
        atomicAdd(acc, a);
        __threadfence();
        int old = atomicAdd(cntr, 1);
        if (old == 1023) {
            __threadfence();
            float tot = atomicAdd(acc, 0.0f);
            out[0] = tot * (0.1f / 8192.0f);
        }
    }
}

extern "C" void kernel_launch(void* const* d_in, const int* in_sizes, int n_in,
                              void* d_out, int out_size, void* d_ws, size_t ws_size,
                              hipStream_t stream) {
    const float* feat = (const float*)d_in[0];    // 8192 x 256 fp32
    const int* labels = (const int*)d_in[1];      // 4096
    float* out = (float*)d_out;

    char* ws = (char*)d_ws;
    ushort_t* Fb = (ushort_t*)ws;                                // 4 MB
    float* part  = (float*)(ws + (4u << 20));                    // 1 MB (8192 x 16 x 8B)
    int* cnt     = (int*)(ws + (5u << 20));                      // 4 KB
    float* acc   = (float*)(ws + (5u << 20) + 4096);             // 4 B
    int* cntr    = (int*)(ws + (5u << 20) + 4100);               // 4 B
    int* idxl    = (int*)(ws + (5u << 20) + 8192);               // 256 KB

    hipMemsetAsync(cnt, 0, 4104, stream);                        // cnt + acc + cntr
    prep_kernel<<<2048, 256, 0, stream>>>(feat, labels, Fb, cnt, idxl);
    dim3 grid(64, 4);
    supcon_main<<<grid, 512, 131072, stream>>>(Fb, part);
    combine_kernel<<<1024, 256, 0, stream>>>(part, feat, cnt, idxl, acc, cntr, out);
}